// Round 5
// baseline (292.153 us; speedup 1.0000x reference)
//
#include <hip/hip_runtime.h>
#include <hip/hip_cooperative_groups.h>

namespace cg = cooperative_groups;

namespace {

constexpr int Hh   = 256;
constexpr int Ww   = 256;
constexpr int IMG  = Hh * Ww;            // 65536
constexpr int NV   = (Hh - 1) * Ww;      // 65280 vertical candidates
constexpr int NC   = NV + Hh * (Ww - 1); // 130560 total candidates
constexpr int PMAX = 8192;
constexpr int CB   = 256;                // candidate block
constexpr int NCB  = (NC + CB - 1) / CB; // 510
constexpr int NB   = 4;                  // batch
constexpr int NIMG = 2 * NB;             // 8 images (pred 0..3, gt 4..7)
constexpr float EPSF = 1e-8f;
constexpr int TCH  = 8;                  // chamfer target chunks
constexpr int CHK  = PMAX / TCH;         // 1024 targets per chunk (8 KB LDS)
constexpr int QB   = PMAX / CB;          // 32 query blocks per combo
constexpr int NTASK = NIMG * NCB;        // 4080 extract tasks
constexpr int CT    = QB * TCH * NIMG;   // 2048 chamfer tasks
constexpr int GRID  = 512;               // cooperative grid (2 blocks/CU)

// Candidate c -> (point, valid). Order matches reference: vertical block
// (row-major over (H-1)xW) then horizontal block (row-major over Hx(W-1)).
__device__ inline bool cand_pt(const float* img, int c, float2& pt) {
  if (c < NV) {
    int i = c >> 8, j = c & 255;             // W == 256
    float v1 = img[i * Ww + j];
    float v2 = img[(i + 1) * Ww + j];
    bool valid = (v1 == 0.f) | (v2 == 0.f) | (v1 * v2 < 0.f);
    float a = fabsf(v1) / (fabsf(v1) + fabsf(v2) + EPSF);
    float row = (v1 == 0.f) ? (float)i
              : ((v2 == 0.f) ? (float)(i + 1) : (float)i + a);
    pt.x = row; pt.y = (float)j;
    return valid;
  } else {
    int cc = c - NV;
    int i = cc / (Ww - 1);
    int j = cc - i * (Ww - 1);
    float h1 = img[i * Ww + j];
    float h2 = img[i * Ww + j + 1];
    bool valid = (h1 == 0.f) | (h2 == 0.f) | (h1 * h2 < 0.f);
    float a = fabsf(h1) / (fabsf(h1) + fabsf(h2) + EPSF);
    float col = (h1 == 0.f) ? (float)j
              : ((h2 == 0.f) ? (float)(j + 1) : (float)j + a);
    pt.x = (float)i; pt.y = col;
    return valid;
  }
}

__device__ inline const float* img_ptr(const float* pred, const float* gt, int img) {
  return (img < NB) ? pred + img * IMG : gt + (img - NB) * IMG;
}

__device__ inline void min_step(float2 p, float2 t, float& m) {
  float dx = p.x - t.x;
  float dy = p.y - t.y;
  m = fminf(m, dx * dx + dy * dy);
}

union SM {
  int    ps[256];     // scan pair-prefixes
  int    iw[4];       // per-wave ints (counts / offsets)
  float  wred[4];     // per-wave float partials
  float2 tgt[CHK];    // chamfer target tile (8 KB)
  float  csum[NIMG];  // final per-combo sums
};

__global__ __launch_bounds__(256, 2)
void fused_kernel(const float* __restrict__ pred,
                  const float* __restrict__ gt,
                  int* __restrict__ counts,
                  float* __restrict__ sums,
                  float* __restrict__ sdfsums,
                  int* __restrict__ bCounts,
                  int* __restrict__ bOffs,
                  float* __restrict__ l1part,
                  float2* __restrict__ pts,
                  unsigned int* __restrict__ minq,
                  float* __restrict__ out) {
  cg::grid_group grid = cg::this_grid();
  __shared__ SM sm;
  int tid  = threadIdx.x;
  int lane = tid & 63, wid = tid >> 6;

  // ---- Phase 0: re-init minq (consumed in phase 4, after grid syncs) ----
  for (int idx = blockIdx.x * CB + tid; idx < NIMG * PMAX; idx += GRID * CB)
    minq[idx] = 0x7F7F7F7Fu;                      // ~3.39e38 as float

  // ---- Phase 1: per-task valid counts + L1 partials (no atomics) ----
  for (int task = blockIdx.x; task < NTASK; task += GRID) {
    int img = task / NCB;
    int cb  = task - img * NCB;
    const float* im = img_ptr(pred, gt, img);
    int c = cb * CB + tid;
    bool valid = false;
    float2 pt;
    if (c < NC) valid = cand_pt(im, c, pt);
    unsigned long long bal = __ballot(valid);
    if (lane == 0) sm.iw[wid] = __popcll(bal);
    __syncthreads();
    if (tid == 0)
      bCounts[task] = sm.iw[0] + sm.iw[1] + sm.iw[2] + sm.iw[3];
    __syncthreads();
    if (img < NB && cb < IMG / CB) {              // block-uniform branch
      float v = fabsf(pred[img * IMG + c] - gt[img * IMG + c]);
      for (int off = 32; off > 0; off >>= 1) v += __shfl_down(v, off, 64);
      if (lane == 0) sm.wred[wid] = v;
      __syncthreads();
      if (tid == 0)
        l1part[img * (IMG / CB) + cb] = sm.wred[0] + sm.wred[1] + sm.wred[2] + sm.wred[3];
    }
    __syncthreads();
  }
  grid.sync();

  // ---- Phase 2: per-image exclusive scan of 510 block counts (8 blocks) ----
  if (blockIdx.x < NIMG) {
    int img = blockIdx.x;
    int e0 = (2 * tid     < NCB) ? bCounts[img * NCB + 2 * tid]     : 0;
    int e1 = (2 * tid + 1 < NCB) ? bCounts[img * NCB + 2 * tid + 1] : 0;
    int p = e0 + e1;
    sm.ps[tid] = p;
    __syncthreads();
    for (int off = 1; off < 256; off <<= 1) {
      int x = sm.ps[tid];
      int y = (tid >= off) ? sm.ps[tid - off] : 0;
      __syncthreads();
      sm.ps[tid] = x + y;
      __syncthreads();
    }
    int excl = sm.ps[tid] - p;                    // exclusive prefix of elem 2*tid
    if (2 * tid     < NCB) bOffs[img * NCB + 2 * tid]     = excl;
    if (2 * tid + 1 < NCB) bOffs[img * NCB + 2 * tid + 1] = excl + e0;
    if (tid == 255) counts[img] = min(sm.ps[255], PMAX);
  }
  grid.sync();

  // ---- Phase 3: order-preserving compacted write (recompute candidates) ----
  for (int task = blockIdx.x; task < NTASK; task += GRID) {
    int img = task / NCB;
    int cb  = task - img * NCB;
    const float* im = img_ptr(pred, gt, img);
    int c = cb * CB + tid;
    bool valid = false;
    float2 pt;
    if (c < NC) valid = cand_pt(im, c, pt);
    unsigned long long bal = __ballot(valid);
    if (lane == 0) sm.iw[wid] = __popcll(bal);
    __syncthreads();
    int wofs = 0;
    for (int w = 0; w < CB / 64; ++w) wofs += (wid > w) ? sm.iw[w] : 0;
    if (valid) {
      int rank = bOffs[task] + wofs + __popcll(bal & ((1ull << lane) - 1ull));
      if (rank < PMAX) pts[img * PMAX + rank] = pt;
    }
    __syncthreads();
  }
  grid.sync();

  // ---- Phase 4: chamfer partial mins, atomicMin merge (64K addresses) ----
  for (int ct = blockIdx.x; ct < CT; ct += GRID) {
    int qb  = ct & (QB - 1);
    int ych = (ct / QB) & (TCH - 1);
    int z   = ct / (QB * TCH);
    int b = z & (NB - 1), dir = z / NB;
    int qimg = (dir == 0) ? b : NB + b;
    int timg = (dir == 0) ? NB + b : b;
    int nq = counts[qimg], nt = counts[timg];
    if (nq == 0 || nt == 0) continue;             // block-uniform skips
    int qbase = qb * CB;
    if (qbase >= nq) continue;
    int len = (nt + TCH - 1) / TCH;
    int ts  = ych * len;
    if (ts >= nt) continue;
    int cnt = min(len, nt - ts);

    for (int t = tid; t < cnt; t += CB)
      sm.tgt[t] = pts[timg * PMAX + ts + t];
    __syncthreads();

    int q = qbase + tid;
    float2 p = (q < nq) ? pts[qimg * PMAX + q] : make_float2(0.f, 0.f);
    float m0 = 3.4e38f, m1 = 3.4e38f, m2 = 3.4e38f, m3 = 3.4e38f;
    int j = 0;
    for (; j + 4 <= cnt; j += 4) {                // 4 independent min chains
      min_step(p, sm.tgt[j + 0], m0);
      min_step(p, sm.tgt[j + 1], m1);
      min_step(p, sm.tgt[j + 2], m2);
      min_step(p, sm.tgt[j + 3], m3);
    }
    for (; j < cnt; ++j) min_step(p, sm.tgt[j], m0);
    float m = fminf(fminf(m0, m1), fminf(m2, m3));
    if (q < nq)
      atomicMin(&minq[z * PMAX + q], __float_as_uint(m));
    __syncthreads();
  }
  grid.sync();

  // ---- Phase 5: reductions (blocks 0..7: chamfer sums, 8..11: L1) ----
  if (blockIdx.x < NIMG) {
    int combo = blockIdx.x;                       // dir*NB + b
    int dir = combo / NB, b = combo & (NB - 1);
    int qimg = (dir == 0) ? b : NB + b;
    int nq = counts[qimg];
    float s = 0.f;
    for (int q = tid; q < nq; q += CB)
      s += sqrtf(__uint_as_float(minq[combo * PMAX + q]));
    for (int off = 32; off > 0; off >>= 1) s += __shfl_down(s, off, 64);
    if (lane == 0) sm.wred[wid] = s;
    __syncthreads();
    if (tid == 0)
      sums[combo] = sm.wred[0] + sm.wred[1] + sm.wred[2] + sm.wred[3];
  } else if (blockIdx.x < NIMG + NB) {
    int b = blockIdx.x - NIMG;
    float s = l1part[b * (IMG / CB) + tid];       // 256 partials, 256 threads
    for (int off = 32; off > 0; off >>= 1) s += __shfl_down(s, off, 64);
    if (lane == 0) sm.wred[wid] = s;
    __syncthreads();
    if (tid == 0)
      sdfsums[b] = sm.wred[0] + sm.wred[1] + sm.wred[2] + sm.wred[3];
  }
  grid.sync();

  // ---- Phase 6: combine ----
  if (blockIdx.x == 0 && tid == 0) {
    float total = 0.f;
    for (int b = 0; b < NB; ++b) {
      float n1 = (float)counts[b];
      float n2 = (float)counts[NB + b];
      float mean1 = sums[b]      / fmaxf(n1, 1.f);
      float mean2 = sums[NB + b] / fmaxf(n2, 1.f);
      float cd = -mean1 + mean2;
      float ch = (n1 > 0.f && n2 > 0.f) ? fabsf(cd) : 0.f;
      total += ch + sdfsums[b] * (1.f / (float)IMG);
    }
    out[0] = total * (1.f / (float)NB);
  }
}

} // namespace

extern "C" void kernel_launch(void* const* d_in, const int* in_sizes, int n_in,
                              void* d_out, int out_size, void* d_ws, size_t ws_size,
                              hipStream_t stream) {
  const float* pred = (const float*)d_in[0];
  const float* gt   = (const float*)d_in[1];
  float* out = (float*)d_out;

  char* ws = (char*)d_ws;    // ws_size ~256 MB (harness poison fill = 268 MB)
  // layout (bytes):
  //   [0,32)            float sums[8]
  //   [32,48)           float sdfsums[4]
  //   [64,96)           int counts[8]
  //   [4096,  +16320)   int bCounts[8*510]
  //   [24576, +16320)   int bOffs[8*510]
  //   [45056, +4096)    float l1part[4*256]
  //   [65536, +524288)  float2 pts[8*8192]
  //   [1048576,+262144) uint minq[8*8192]
  float*        sums    = (float*)(ws + 0);
  float*        sdfsums = (float*)(ws + 32);
  int*          counts  = (int*)(ws + 64);
  int*          bCounts = (int*)(ws + 4096);
  int*          bOffs   = (int*)(ws + 24576);
  float*        l1part  = (float*)(ws + 45056);
  float2*       pts     = (float2*)(ws + 65536);
  unsigned int* minq    = (unsigned int*)(ws + 1048576);

  void* args[] = {
    (void*)&pred, (void*)&gt, (void*)&counts, (void*)&sums, (void*)&sdfsums,
    (void*)&bCounts, (void*)&bOffs, (void*)&l1part, (void*)&pts, (void*)&minq,
    (void*)&out,
  };
  hipLaunchCooperativeKernel((const void*)fused_kernel, dim3(GRID), dim3(CB),
                             args, 0, stream);
}

// Round 7
// 57.185 us; speedup vs baseline: 5.1089x; 5.1089x over previous
//
#include <hip/hip_runtime.h>

namespace {

constexpr int Hh   = 256;
constexpr int Ww   = 256;
constexpr int IMG  = Hh * Ww;            // 65536
constexpr int NV   = (Hh - 1) * Ww;      // 65280 vertical candidates
constexpr int NC   = NV + Hh * (Ww - 1); // 130560 total candidates
constexpr int PMAX = 8192;
constexpr int CB   = 256;                // candidate block
constexpr int NCB  = (NC + CB - 1) / CB; // 510
constexpr int NB   = 4;                  // batch
constexpr int NIMG = 2 * NB;             // 8 images (pred 0..3, gt 4..7)
constexpr float EPSF = 1e-8f;
constexpr int TCH  = 8;                  // chamfer target chunks
constexpr int CHK  = PMAX / TCH;         // 1024 targets per chunk (8 KB LDS)
constexpr int CPAD = 32;                 // ints between counters (128 B, own line)

// Candidate c -> (point, valid). Vertical block (row-major over (H-1)xW)
// then horizontal block (row-major over Hx(W-1)), as in the reference.
// Compaction order is NOT preserved (block-atomic ranks) — valid because
// chamfer min / means are order-invariant over the point set and actual
// valid counts (~2k) are far below PMAX, so no truncation occurs.
__device__ inline bool cand_pt(const float* img, int c, float2& pt) {
  if (c < NV) {
    int i = c >> 8, j = c & 255;             // W == 256
    float v1 = img[i * Ww + j];
    float v2 = img[(i + 1) * Ww + j];
    bool valid = (v1 == 0.f) | (v2 == 0.f) | (v1 * v2 < 0.f);
    float a = fabsf(v1) / (fabsf(v1) + fabsf(v2) + EPSF);
    float row = (v1 == 0.f) ? (float)i
              : ((v2 == 0.f) ? (float)(i + 1) : (float)i + a);
    pt.x = row; pt.y = (float)j;
    return valid;
  } else {
    int cc = c - NV;
    int i = cc / (Ww - 1);
    int j = cc - i * (Ww - 1);
    float h1 = img[i * Ww + j];
    float h2 = img[i * Ww + j + 1];
    bool valid = (h1 == 0.f) | (h2 == 0.f) | (h1 * h2 < 0.f);
    float a = fabsf(h1) / (fabsf(h1) + fabsf(h2) + EPSF);
    float col = (h1 == 0.f) ? (float)j
              : ((h2 == 0.f) ? (float)(j + 1) : (float)j + a);
    pt.x = (float)i; pt.y = col;
    return valid;
  }
}

__device__ inline const float* img_ptr(const float* pred, const float* gt, int img) {
  return (img < NB) ? pred + img * IMG : gt + (img - NB) * IMG;
}

// Kernel 1: zero the 8 padded counters.
__global__ void init_kernel(int* __restrict__ counts_pad) {
  counts_pad[threadIdx.x] = 0;                   // 256 threads cover 8*32 ints
}

// Kernel 2: fused extract = minq re-init + candidate eval + block-atomic
// compaction (ONE atomicAdd per block, counters on separate cachelines)
// + L1 |pred-gt| per-block partials.
__global__ void extract_kernel(const float* __restrict__ pred,
                               const float* __restrict__ gt,
                               int* __restrict__ counts_pad,
                               float* __restrict__ l1part,
                               float2* __restrict__ pts,
                               unsigned int* __restrict__ minq) {
  int img = blockIdx.y;
  int cb  = blockIdx.x;
  const float* im = img_ptr(pred, gt, img);
  int tid = threadIdx.x;
  int c = cb * CB + tid;
  int lane = tid & 63, wid = tid >> 6;

  // fused: re-init minq (combo index space == img index space, 8*8192)
  if (cb < PMAX / CB)
    minq[img * PMAX + c] = 0x7F7F7F7Fu;          // ~3.39e38 as float

  bool valid = false;
  float2 pt;
  if (c < NC) valid = cand_pt(im, c, pt);

  unsigned long long bal = __ballot(valid);
  __shared__ int iw[CB / 64];
  __shared__ int sbase;
  __shared__ float wred[CB / 64];
  if (lane == 0) iw[wid] = __popcll(bal);
  __syncthreads();
  if (tid == 0) {
    int run = 0;
    for (int w = 0; w < CB / 64; ++w) { int t = iw[w]; iw[w] = run; run += t; }
    sbase = run ? atomicAdd(&counts_pad[img * CPAD], run) : 0;
  }
  __syncthreads();
  if (valid) {
    int rank = sbase + iw[wid] + __popcll(bal & ((1ull << lane) - 1ull));
    if (rank < PMAX) pts[img * PMAX + rank] = pt;
  }

  // fused L1 partial (pred images only; pixel blocks only; c < IMG there)
  if (img < NB && cb < IMG / CB) {
    float v = fabsf(pred[img * IMG + c] - gt[img * IMG + c]);
    for (int off = 32; off > 0; off >>= 1) v += __shfl_down(v, off, 64);
    if (lane == 0) wred[wid] = v;
    __syncthreads();
    if (tid == 0)
      l1part[img * (IMG / CB) + cb] = wred[0] + wred[1] + wred[2] + wred[3];
  }
}

__device__ inline void min_step(float2 p, float2 t, float& m) {
  float dx = p.x - t.x;
  float dy = p.y - t.y;
  m = fminf(m, dx * dx + dy * dy);
}

// Kernel 3: partial chamfer. grid = (PMAX/256 qblocks, TCH tchunks, 2*NB).
// Each block: partial min^2 over its target chunk for its 256 queries,
// merged via uint atomicMin to 64K distinct addresses (no contention;
// valid since d2 >= 0 makes IEEE bits order-monotone).
__global__ void chamfer_kernel(const float2* __restrict__ pts,
                               const int* __restrict__ counts_pad,
                               unsigned int* __restrict__ minq) {
  int b   = blockIdx.z & (NB - 1);
  int dir = blockIdx.z / NB;
  int qimg = (dir == 0) ? b : NB + b;
  int timg = (dir == 0) ? NB + b : b;
  int nq = min(counts_pad[qimg * CPAD], PMAX);
  int nt = min(counts_pad[timg * CPAD], PMAX);
  if (nq == 0 || nt == 0) return;                  // block-uniform
  int qbase = blockIdx.x * 256;
  if (qbase >= nq) return;
  int len = (nt + TCH - 1) / TCH;
  int ts  = blockIdx.y * len;
  if (ts >= nt) return;
  int cnt = min(len, nt - ts);

  __shared__ float2 tgt[CHK];
  for (int t = threadIdx.x; t < cnt; t += 256)
    tgt[t] = pts[timg * PMAX + ts + t];
  __syncthreads();

  int q = qbase + threadIdx.x;
  float2 p = (q < nq) ? pts[qimg * PMAX + q] : make_float2(0.f, 0.f);
  float m0 = 3.4e38f, m1 = 3.4e38f, m2 = 3.4e38f, m3 = 3.4e38f;
  int j = 0;
  for (; j + 4 <= cnt; j += 4) {                   // 4 independent min chains
    min_step(p, tgt[j + 0], m0);
    min_step(p, tgt[j + 1], m1);
    min_step(p, tgt[j + 2], m2);
    min_step(p, tgt[j + 3], m3);
  }
  for (; j < cnt; ++j) min_step(p, tgt[j], m0);
  float m = fminf(fminf(m0, m1), fminf(m2, m3));

  if (q < nq)
    atomicMin(&minq[(dir * NB + b) * PMAX + q], __float_as_uint(m));
}

// Kernel 4: single-block tail = chamfer sqrt-sum reduces + L1 reduces + combine.
__global__ void tail_kernel(const unsigned int* __restrict__ minq,
                            const int* __restrict__ counts_pad,
                            const float* __restrict__ l1part,
                            float* __restrict__ out) {
  __shared__ float csum[NIMG];
  __shared__ float sdf[NB];
  __shared__ float wsum[4];
  int tid = threadIdx.x;
  int lane = tid & 63, wid = tid >> 6;

  for (int combo = 0; combo < NIMG; ++combo) {
    int dir = combo / NB, b = combo & (NB - 1);
    int qimg = (dir == 0) ? b : NB + b;
    int nq = min(counts_pad[qimg * CPAD], PMAX);
    float s = 0.f;
    for (int q = tid; q < nq; q += 256)
      s += sqrtf(__uint_as_float(minq[combo * PMAX + q]));
    for (int off = 32; off > 0; off >>= 1) s += __shfl_down(s, off, 64);
    if (lane == 0) wsum[wid] = s;
    __syncthreads();
    if (tid == 0) csum[combo] = wsum[0] + wsum[1] + wsum[2] + wsum[3];
    __syncthreads();
  }
  for (int b = 0; b < NB; ++b) {
    float s = l1part[b * (IMG / CB) + tid];        // 256 partials, 256 threads
    for (int off = 32; off > 0; off >>= 1) s += __shfl_down(s, off, 64);
    if (lane == 0) wsum[wid] = s;
    __syncthreads();
    if (tid == 0) sdf[b] = wsum[0] + wsum[1] + wsum[2] + wsum[3];
    __syncthreads();
  }
  if (tid == 0) {
    float total = 0.f;
    for (int b = 0; b < NB; ++b) {
      float n1 = (float)min(counts_pad[b * CPAD], PMAX);
      float n2 = (float)min(counts_pad[(NB + b) * CPAD], PMAX);
      float mean1 = csum[b]      / fmaxf(n1, 1.f);
      float mean2 = csum[NB + b] / fmaxf(n2, 1.f);
      float cd = -mean1 + mean2;
      float ch = (n1 > 0.f && n2 > 0.f) ? fabsf(cd) : 0.f;
      total += ch + sdf[b] * (1.f / (float)IMG);
    }
    out[0] = total * (1.f / (float)NB);
  }
}

} // namespace

extern "C" void kernel_launch(void* const* d_in, const int* in_sizes, int n_in,
                              void* d_out, int out_size, void* d_ws, size_t ws_size,
                              hipStream_t stream) {
  const float* pred = (const float*)d_in[0];
  const float* gt   = (const float*)d_in[1];
  float* out = (float*)d_out;

  char* ws = (char*)d_ws;
  // layout (bytes):
  //   [0, +1024)        int counts_pad[8*32]  (one counter per 128 B line)
  //   [4096, +4096)     float l1part[4*256]
  //   [65536, +524288)  float2 pts[8*8192]
  //   [1048576,+262144) uint minq[8*8192]   (re-init in extract_kernel)
  int*          counts_pad = (int*)(ws + 0);
  float*        l1part     = (float*)(ws + 4096);
  float2*       pts        = (float2*)(ws + 65536);
  unsigned int* minq       = (unsigned int*)(ws + 1048576);

  init_kernel<<<1, 256, 0, stream>>>(counts_pad);
  extract_kernel<<<dim3(NCB, NIMG), CB, 0, stream>>>(pred, gt, counts_pad,
                                                     l1part, pts, minq);
  chamfer_kernel<<<dim3(PMAX / CB, TCH, NIMG), 256, 0, stream>>>(pts, counts_pad,
                                                                 minq);
  tail_kernel<<<1, 256, 0, stream>>>(minq, counts_pad, l1part, out);
}

// Round 8
// 42.160 us; speedup vs baseline: 6.9297x; 1.3564x over previous
//
#include <hip/hip_runtime.h>

namespace {

constexpr int Hh   = 256;
constexpr int Ww   = 256;
constexpr int IMG  = Hh * Ww;            // 65536
constexpr int NV   = (Hh - 1) * Ww;      // 65280 vertical candidates
constexpr int NC   = NV + Hh * (Ww - 1); // 130560 total candidates
constexpr int PMAX = 8192;
constexpr int CB   = 256;                // candidate block
constexpr int NCB  = (NC + CB - 1) / CB; // 510
constexpr int NB   = 4;                  // batch
constexpr int NIMG = 2 * NB;             // 8 images (pred 0..3, gt 4..7)
constexpr float EPSF = 1e-8f;
constexpr int TCH  = 8;                  // chamfer target chunks
constexpr int CHK  = PMAX / TCH;         // 1024 targets per chunk (8 KB LDS)

// Candidate c -> (point, valid). Vertical block (row-major over (H-1)xW)
// then horizontal block (row-major over Hx(W-1)), matching the reference.
// Compaction is ORDER-PRESERVING (prefix-sum ranks), so the first-8192
// truncation semantics match the reference exactly.
__device__ inline bool cand_pt(const float* img, int c, float2& pt) {
  if (c < NV) {
    int i = c >> 8, j = c & 255;             // W == 256
    float v1 = img[i * Ww + j];
    float v2 = img[(i + 1) * Ww + j];
    bool valid = (v1 == 0.f) | (v2 == 0.f) | (v1 * v2 < 0.f);
    float a = fabsf(v1) / (fabsf(v1) + fabsf(v2) + EPSF);
    float row = (v1 == 0.f) ? (float)i
              : ((v2 == 0.f) ? (float)(i + 1) : (float)i + a);
    pt.x = row; pt.y = (float)j;
    return valid;
  } else {
    int cc = c - NV;
    int i = cc / (Ww - 1);
    int j = cc - i * (Ww - 1);
    float h1 = img[i * Ww + j];
    float h2 = img[i * Ww + j + 1];
    bool valid = (h1 == 0.f) | (h2 == 0.f) | (h1 * h2 < 0.f);
    float a = fabsf(h1) / (fabsf(h1) + fabsf(h2) + EPSF);
    float col = (h1 == 0.f) ? (float)j
              : ((h2 == 0.f) ? (float)(j + 1) : (float)j + a);
    pt.x = (float)i; pt.y = col;
    return valid;
  }
}

__device__ inline const float* img_ptr(const float* pred, const float* gt, int img) {
  return (img < NB) ? pred + img * IMG : gt + (img - NB) * IMG;
}

// Kernel 1: per-block valid counts (plain store), minq re-init, L1 partials.
// No atomics anywhere.
__global__ void count_kernel(const float* __restrict__ pred,
                             const float* __restrict__ gt,
                             int* __restrict__ bCounts,
                             float* __restrict__ l1part,
                             unsigned int* __restrict__ minq) {
  int img = blockIdx.y;
  int cb  = blockIdx.x;
  const float* im = img_ptr(pred, gt, img);
  int tid = threadIdx.x;
  int c = cb * CB + tid;
  int lane = tid & 63, wid = tid >> 6;

  // fused: re-init minq (combo index space == img index space, 8*8192)
  if (cb < PMAX / CB)
    minq[img * PMAX + c] = 0x7F7F7F7Fu;          // ~3.39e38 as float

  bool valid = false;
  float2 pt;
  if (c < NC) valid = cand_pt(im, c, pt);
  unsigned long long bal = __ballot(valid);

  __shared__ int   iw[CB / 64];
  __shared__ float wred[CB / 64];
  if (lane == 0) iw[wid] = __popcll(bal);
  __syncthreads();
  if (tid == 0)
    bCounts[img * NCB + cb] = iw[0] + iw[1] + iw[2] + iw[3];

  // fused L1 partial (pred images only; pixel blocks only; c < IMG there)
  if (img < NB && cb < IMG / CB) {
    float v = fabsf(pred[img * IMG + c] - gt[img * IMG + c]);
    for (int off = 32; off > 0; off >>= 1) v += __shfl_down(v, off, 64);
    if (lane == 0) wred[wid] = v;
    __syncthreads();
    if (tid == 0)
      l1part[img * (IMG / CB) + cb] = wred[0] + wred[1] + wred[2] + wred[3];
  }
}

// Kernel 2: order-preserving compacted write. Each block recomputes its own
// exclusive prefix over bCounts[img][0..cb) (<=510 ints, L2-hot) — the scan
// kernel is fused away. Last block per image also writes counts[img].
__global__ void write_kernel(const float* __restrict__ pred,
                             const float* __restrict__ gt,
                             const int* __restrict__ bCounts,
                             int* __restrict__ counts,
                             float2* __restrict__ pts) {
  int img = blockIdx.y;
  int cb  = blockIdx.x;
  const float* im = img_ptr(pred, gt, img);
  int tid = threadIdx.x;
  int c = cb * CB + tid;
  int lane = tid & 63, wid = tid >> 6;

  bool valid = false;
  float2 pt;
  if (c < NC) valid = cand_pt(im, c, pt);
  unsigned long long bal = __ballot(valid);

  // block-wide prefix of bCounts[img][0..cb)
  int pre = 0;
  for (int t = tid; t < cb; t += CB) pre += bCounts[img * NCB + t];
  for (int off = 32; off > 0; off >>= 1) pre += __shfl_down(pre, off, 64);
  __shared__ int pw[CB / 64];
  __shared__ int iw[CB / 64];
  if (lane == 0) pw[wid] = pre;
  if (lane == 0) iw[wid] = __popcll(bal);
  __syncthreads();
  int sbase = pw[0] + pw[1] + pw[2] + pw[3];       // exclusive image prefix
  int wofs = 0;
  for (int w = 0; w < CB / 64; ++w) wofs += (w < wid) ? iw[w] : 0;

  if (valid) {
    int rank = sbase + wofs + __popcll(bal & ((1ull << lane) - 1ull));
    if (rank < PMAX) pts[img * PMAX + rank] = pt;
  }
  if (cb == NCB - 1 && tid == 0) {
    int total = sbase + iw[0] + iw[1] + iw[2] + iw[3];
    counts[img] = min(total, PMAX);
  }
}

__device__ inline void min_step(float2 p, float2 t, float& m) {
  float dx = p.x - t.x;
  float dy = p.y - t.y;
  m = fminf(m, dx * dx + dy * dy);
}

// Kernel 3: partial chamfer. grid = (PMAX/256 qblocks, TCH tchunks, 2*NB).
// Each block: partial min^2 over its target chunk for its 256 queries,
// merged via uint atomicMin to 64K distinct addresses (no contention;
// valid since d2 >= 0 makes IEEE bits order-monotone).
__global__ void chamfer_kernel(const float2* __restrict__ pts,
                               const int* __restrict__ counts,
                               unsigned int* __restrict__ minq) {
  int b   = blockIdx.z & (NB - 1);
  int dir = blockIdx.z / NB;
  int qimg = (dir == 0) ? b : NB + b;
  int timg = (dir == 0) ? NB + b : b;
  int nq = counts[qimg], nt = counts[timg];
  if (nq == 0 || nt == 0) return;                  // block-uniform
  int qbase = blockIdx.x * 256;
  if (qbase >= nq) return;
  int len = (nt + TCH - 1) / TCH;
  int ts  = blockIdx.y * len;
  if (ts >= nt) return;
  int cnt = min(len, nt - ts);

  __shared__ float2 tgt[CHK];
  for (int t = threadIdx.x; t < cnt; t += 256)
    tgt[t] = pts[timg * PMAX + ts + t];
  __syncthreads();

  int q = qbase + threadIdx.x;
  float2 p = (q < nq) ? pts[qimg * PMAX + q] : make_float2(0.f, 0.f);
  float m0 = 3.4e38f, m1 = 3.4e38f, m2 = 3.4e38f, m3 = 3.4e38f;
  int j = 0;
  for (; j + 4 <= cnt; j += 4) {                   // 4 independent min chains
    min_step(p, tgt[j + 0], m0);
    min_step(p, tgt[j + 1], m1);
    min_step(p, tgt[j + 2], m2);
    min_step(p, tgt[j + 3], m3);
  }
  for (; j < cnt; ++j) min_step(p, tgt[j], m0);
  float m = fminf(fminf(m0, m1), fminf(m2, m3));

  if (q < nq)
    atomicMin(&minq[(dir * NB + b) * PMAX + q], __float_as_uint(m));
}

// Kernel 4: single-block tail = chamfer sqrt-sum reduces + L1 reduces + combine.
__global__ void tail_kernel(const unsigned int* __restrict__ minq,
                            const int* __restrict__ counts,
                            const float* __restrict__ l1part,
                            float* __restrict__ out) {
  __shared__ float csum[NIMG];
  __shared__ float sdf[NB];
  __shared__ float wsum[4];
  int tid = threadIdx.x;
  int lane = tid & 63, wid = tid >> 6;

  for (int combo = 0; combo < NIMG; ++combo) {
    int dir = combo / NB, b = combo & (NB - 1);
    int qimg = (dir == 0) ? b : NB + b;
    int nq = counts[qimg];
    float s = 0.f;
    for (int q = tid; q < nq; q += 256)
      s += sqrtf(__uint_as_float(minq[combo * PMAX + q]));
    for (int off = 32; off > 0; off >>= 1) s += __shfl_down(s, off, 64);
    if (lane == 0) wsum[wid] = s;
    __syncthreads();
    if (tid == 0) csum[combo] = wsum[0] + wsum[1] + wsum[2] + wsum[3];
    __syncthreads();
  }
  for (int b = 0; b < NB; ++b) {
    float s = l1part[b * (IMG / CB) + tid];        // 256 partials, 256 threads
    for (int off = 32; off > 0; off >>= 1) s += __shfl_down(s, off, 64);
    if (lane == 0) wsum[wid] = s;
    __syncthreads();
    if (tid == 0) sdf[b] = wsum[0] + wsum[1] + wsum[2] + wsum[3];
    __syncthreads();
  }
  if (tid == 0) {
    float total = 0.f;
    for (int b = 0; b < NB; ++b) {
      float n1 = (float)counts[b];
      float n2 = (float)counts[NB + b];
      float mean1 = csum[b]      / fmaxf(n1, 1.f);
      float mean2 = csum[NB + b] / fmaxf(n2, 1.f);
      float cd = -mean1 + mean2;
      float ch = (n1 > 0.f && n2 > 0.f) ? fabsf(cd) : 0.f;
      total += ch + sdf[b] * (1.f / (float)IMG);
    }
    out[0] = total * (1.f / (float)NB);
  }
}

} // namespace

extern "C" void kernel_launch(void* const* d_in, const int* in_sizes, int n_in,
                              void* d_out, int out_size, void* d_ws, size_t ws_size,
                              hipStream_t stream) {
  const float* pred = (const float*)d_in[0];
  const float* gt   = (const float*)d_in[1];
  float* out = (float*)d_out;

  char* ws = (char*)d_ws;
  // layout (bytes):
  //   [0, +32)          int counts[8]        (written by write_kernel)
  //   [4096, +16320)    int bCounts[8*510]
  //   [24576, +4096)    float l1part[4*256]
  //   [65536, +524288)  float2 pts[8*8192]
  //   [1048576,+262144) uint minq[8*8192]    (re-init in count_kernel)
  int*          counts  = (int*)(ws + 0);
  int*          bCounts = (int*)(ws + 4096);
  float*        l1part  = (float*)(ws + 24576);
  float2*       pts     = (float2*)(ws + 65536);
  unsigned int* minq    = (unsigned int*)(ws + 1048576);

  count_kernel<<<dim3(NCB, NIMG), CB, 0, stream>>>(pred, gt, bCounts, l1part, minq);
  write_kernel<<<dim3(NCB, NIMG), CB, 0, stream>>>(pred, gt, bCounts, counts, pts);
  chamfer_kernel<<<dim3(PMAX / CB, TCH, NIMG), 256, 0, stream>>>(pts, counts, minq);
  tail_kernel<<<1, 256, 0, stream>>>(minq, counts, l1part, out);
}

// Round 9
// 40.308 us; speedup vs baseline: 7.2480x; 1.0459x over previous
//
#include <hip/hip_runtime.h>

namespace {

constexpr int Hh   = 256;
constexpr int Ww   = 256;
constexpr int IMG  = Hh * Ww;            // 65536
constexpr int NV   = (Hh - 1) * Ww;      // 65280 vertical candidates
constexpr int NC   = NV + Hh * (Ww - 1); // 130560 total candidates
constexpr int PMAX = 8192;
constexpr int CB   = 256;                // candidate block
constexpr int NCB  = (NC + CB - 1) / CB; // 510
constexpr int NB   = 4;                  // batch
constexpr int NIMG = 2 * NB;             // 8 images (pred 0..3, gt 4..7)
constexpr float EPSF = 1e-8f;
constexpr int TCH  = 8;                  // chamfer target chunks
constexpr int CHK  = PMAX / TCH;         // 1024 targets per chunk (8 KB LDS)

// Candidate c -> (point, valid). Vertical block (row-major over (H-1)xW)
// then horizontal block (row-major over Hx(W-1)), matching the reference.
// Compaction is ORDER-PRESERVING (prefix-sum ranks), so the first-8192
// truncation semantics match the reference exactly.
__device__ inline bool cand_pt(const float* img, int c, float2& pt) {
  if (c < NV) {
    int i = c >> 8, j = c & 255;             // W == 256
    float v1 = img[i * Ww + j];
    float v2 = img[(i + 1) * Ww + j];
    bool valid = (v1 == 0.f) | (v2 == 0.f) | (v1 * v2 < 0.f);
    float a = fabsf(v1) / (fabsf(v1) + fabsf(v2) + EPSF);
    float row = (v1 == 0.f) ? (float)i
              : ((v2 == 0.f) ? (float)(i + 1) : (float)i + a);
    pt.x = row; pt.y = (float)j;
    return valid;
  } else {
    int cc = c - NV;
    int i = cc / (Ww - 1);
    int j = cc - i * (Ww - 1);
    float h1 = img[i * Ww + j];
    float h2 = img[i * Ww + j + 1];
    bool valid = (h1 == 0.f) | (h2 == 0.f) | (h1 * h2 < 0.f);
    float a = fabsf(h1) / (fabsf(h1) + fabsf(h2) + EPSF);
    float col = (h1 == 0.f) ? (float)j
              : ((h2 == 0.f) ? (float)(j + 1) : (float)j + a);
    pt.x = (float)i; pt.y = col;
    return valid;
  }
}

__device__ inline const float* img_ptr(const float* pred, const float* gt, int img) {
  return (img < NB) ? pred + img * IMG : gt + (img - NB) * IMG;
}

// Kernel 1: per-block valid counts (plain store), minq re-init, L1 partials.
// No atomics anywhere.
__global__ void count_kernel(const float* __restrict__ pred,
                             const float* __restrict__ gt,
                             int* __restrict__ bCounts,
                             float* __restrict__ l1part,
                             unsigned int* __restrict__ minq) {
  int img = blockIdx.y;
  int cb  = blockIdx.x;
  const float* im = img_ptr(pred, gt, img);
  int tid = threadIdx.x;
  int c = cb * CB + tid;
  int lane = tid & 63, wid = tid >> 6;

  // fused: re-init minq (combo index space == img index space, 8*8192)
  if (cb < PMAX / CB)
    minq[img * PMAX + c] = 0x7F7F7F7Fu;          // ~3.39e38 as float

  bool valid = false;
  float2 pt;
  if (c < NC) valid = cand_pt(im, c, pt);
  unsigned long long bal = __ballot(valid);

  __shared__ int   iw[CB / 64];
  __shared__ float wred[CB / 64];
  if (lane == 0) iw[wid] = __popcll(bal);
  __syncthreads();
  if (tid == 0)
    bCounts[img * NCB + cb] = iw[0] + iw[1] + iw[2] + iw[3];

  // fused L1 partial (pred images only; pixel blocks only; c < IMG there)
  if (img < NB && cb < IMG / CB) {
    float v = fabsf(pred[img * IMG + c] - gt[img * IMG + c]);
    for (int off = 32; off > 0; off >>= 1) v += __shfl_down(v, off, 64);
    if (lane == 0) wred[wid] = v;
    __syncthreads();
    if (tid == 0)
      l1part[img * (IMG / CB) + cb] = wred[0] + wred[1] + wred[2] + wred[3];
  }
}

// Kernel 2: order-preserving compacted write. Each block recomputes its own
// exclusive prefix over bCounts[img][0..cb) (<=510 ints, L2-hot) — the scan
// kernel is fused away. Last block per image also writes counts[img].
__global__ void write_kernel(const float* __restrict__ pred,
                             const float* __restrict__ gt,
                             const int* __restrict__ bCounts,
                             int* __restrict__ counts,
                             float2* __restrict__ pts) {
  int img = blockIdx.y;
  int cb  = blockIdx.x;
  const float* im = img_ptr(pred, gt, img);
  int tid = threadIdx.x;
  int c = cb * CB + tid;
  int lane = tid & 63, wid = tid >> 6;

  bool valid = false;
  float2 pt;
  if (c < NC) valid = cand_pt(im, c, pt);
  unsigned long long bal = __ballot(valid);

  // block-wide prefix of bCounts[img][0..cb)
  int pre = 0;
  for (int t = tid; t < cb; t += CB) pre += bCounts[img * NCB + t];
  for (int off = 32; off > 0; off >>= 1) pre += __shfl_down(pre, off, 64);
  __shared__ int pw[CB / 64];
  __shared__ int iw[CB / 64];
  if (lane == 0) pw[wid] = pre;
  if (lane == 0) iw[wid] = __popcll(bal);
  __syncthreads();
  int sbase = pw[0] + pw[1] + pw[2] + pw[3];       // exclusive image prefix
  int wofs = 0;
  for (int w = 0; w < CB / 64; ++w) wofs += (w < wid) ? iw[w] : 0;

  if (valid) {
    int rank = sbase + wofs + __popcll(bal & ((1ull << lane) - 1ull));
    if (rank < PMAX) pts[img * PMAX + rank] = pt;
  }
  if (cb == NCB - 1 && tid == 0) {
    int total = sbase + iw[0] + iw[1] + iw[2] + iw[3];
    counts[img] = min(total, PMAX);
  }
}

__device__ inline void min_step(float2 p, float2 t, float& m) {
  float dx = p.x - t.x;
  float dy = p.y - t.y;
  m = fminf(m, dx * dx + dy * dy);
}

// Kernel 3: partial chamfer. grid = (PMAX/256 qblocks, TCH tchunks, 2*NB).
// Each block: partial min^2 over its target chunk for its 256 queries,
// merged via uint atomicMin to 64K distinct addresses (no contention;
// valid since d2 >= 0 makes IEEE bits order-monotone).
__global__ void chamfer_kernel(const float2* __restrict__ pts,
                               const int* __restrict__ counts,
                               unsigned int* __restrict__ minq) {
  int b   = blockIdx.z & (NB - 1);
  int dir = blockIdx.z / NB;
  int qimg = (dir == 0) ? b : NB + b;
  int timg = (dir == 0) ? NB + b : b;
  int nq = counts[qimg], nt = counts[timg];
  if (nq == 0 || nt == 0) return;                  // block-uniform
  int qbase = blockIdx.x * 256;
  if (qbase >= nq) return;
  int len = (nt + TCH - 1) / TCH;
  int ts  = blockIdx.y * len;
  if (ts >= nt) return;
  int cnt = min(len, nt - ts);

  __shared__ float2 tgt[CHK];
  for (int t = threadIdx.x; t < cnt; t += 256)
    tgt[t] = pts[timg * PMAX + ts + t];
  __syncthreads();

  int q = qbase + threadIdx.x;
  float2 p = (q < nq) ? pts[qimg * PMAX + q] : make_float2(0.f, 0.f);
  float m0 = 3.4e38f, m1 = 3.4e38f, m2 = 3.4e38f, m3 = 3.4e38f;
  int j = 0;
  for (; j + 4 <= cnt; j += 4) {                   // 4 independent min chains
    min_step(p, tgt[j + 0], m0);
    min_step(p, tgt[j + 1], m1);
    min_step(p, tgt[j + 2], m2);
    min_step(p, tgt[j + 3], m3);
  }
  for (; j < cnt; ++j) min_step(p, tgt[j], m0);
  float m = fminf(fminf(m0, m1), fminf(m2, m3));

  if (q < nq)
    atomicMin(&minq[(dir * NB + b) * PMAX + q], __float_as_uint(m));
}

// Kernel 4: single-block tail, but ALL reductions in parallel in one pass:
//   - chamfer sums: 32 lanes per combo (8 combos across 256 threads)
//   - L1 sums: one 64-lane wave per sample (4 samples across 4 waves)
// then one barrier and a scalar combine. No serial phase chain.
__global__ void tail_kernel(const unsigned int* __restrict__ minq,
                            const int* __restrict__ counts,
                            const float* __restrict__ l1part,
                            float* __restrict__ out) {
  __shared__ float csum[NIMG];
  __shared__ float sdf[NB];
  int tid = threadIdx.x;

  {                                               // chamfer sqrt-sums
    int combo = tid >> 5;                         // 0..7
    int sl    = tid & 31;
    int dir = combo / NB, b = combo & (NB - 1);
    int qimg = (dir == 0) ? b : NB + b;
    int nq = counts[qimg];
    float s = 0.f;
    for (int q = sl; q < nq; q += 32)             // ~64 pipelined loads
      s += sqrtf(__uint_as_float(minq[combo * PMAX + q]));
    for (int off = 16; off > 0; off >>= 1) s += __shfl_down(s, off, 32);
    if (sl == 0) csum[combo] = s;
  }
  {                                               // L1 sums (256 partials/sample)
    int w = tid >> 6;                             // 0..3 = sample
    int l = tid & 63;
    const float* lp = l1part + w * (IMG / CB);
    float s = lp[l] + lp[l + 64] + lp[l + 128] + lp[l + 192];
    for (int off = 32; off > 0; off >>= 1) s += __shfl_down(s, off, 64);
    if (l == 0) sdf[w] = s;
  }
  __syncthreads();
  if (tid == 0) {
    float total = 0.f;
    for (int b = 0; b < NB; ++b) {
      float n1 = (float)counts[b];
      float n2 = (float)counts[NB + b];
      float mean1 = csum[b]      / fmaxf(n1, 1.f);
      float mean2 = csum[NB + b] / fmaxf(n2, 1.f);
      float cd = -mean1 + mean2;
      float ch = (n1 > 0.f && n2 > 0.f) ? fabsf(cd) : 0.f;
      total += ch + sdf[b] * (1.f / (float)IMG);
    }
    out[0] = total * (1.f / (float)NB);
  }
}

} // namespace

extern "C" void kernel_launch(void* const* d_in, const int* in_sizes, int n_in,
                              void* d_out, int out_size, void* d_ws, size_t ws_size,
                              hipStream_t stream) {
  const float* pred = (const float*)d_in[0];
  const float* gt   = (const float*)d_in[1];
  float* out = (float*)d_out;

  char* ws = (char*)d_ws;
  // layout (bytes):
  //   [0, +32)          int counts[8]        (written by write_kernel)
  //   [4096, +16320)    int bCounts[8*510]
  //   [24576, +4096)    float l1part[4*256]
  //   [65536, +524288)  float2 pts[8*8192]
  //   [1048576,+262144) uint minq[8*8192]    (re-init in count_kernel)
  int*          counts  = (int*)(ws + 0);
  int*          bCounts = (int*)(ws + 4096);
  float*        l1part  = (float*)(ws + 24576);
  float2*       pts     = (float2*)(ws + 65536);
  unsigned int* minq    = (unsigned int*)(ws + 1048576);

  count_kernel<<<dim3(NCB, NIMG), CB, 0, stream>>>(pred, gt, bCounts, l1part, minq);
  write_kernel<<<dim3(NCB, NIMG), CB, 0, stream>>>(pred, gt, bCounts, counts, pts);
  chamfer_kernel<<<dim3(PMAX / CB, TCH, NIMG), 256, 0, stream>>>(pts, counts, minq);
  tail_kernel<<<1, 256, 0, stream>>>(minq, counts, l1part, out);
}